// Round 7
// baseline (1192.901 us; speedup 1.0000x reference)
//
#include <hip/hip_runtime.h>
#include <hip/hip_bf16.h>
#include <math.h>

typedef __hip_bfloat16 bf16;
typedef __attribute__((ext_vector_type(8))) short short8;
typedef __attribute__((ext_vector_type(4))) float f32x4;

#define BB 8
#define LL 2048
#define DD 512
#define FF 1025   // LL/2+1
#define GP 1056   // g padded to 33*32 for ctx K-chunks
#define ATT_SCALE 0.04419417382415922f   // 512^-0.5

__device__ __forceinline__ float b2f(bf16 v) { return __bfloat162float(v); }
__device__ __forceinline__ bf16  f2b(float v) { return __float2bfloat16(v); }

#define MFMA16(a, b, c) __builtin_amdgcn_mfma_f32_16x16x32_bf16((a), (b), (c), 0, 0, 0)

// exact bf16 negation of an 8-element fragment (sign-bit flip)
__device__ __forceinline__ short8 neg8(short8 v) {
    short8 r;
    #pragma unroll
    for (int t = 0; t < 8; ++t) r[t] = (short)(v[t] ^ (short)0x8000);
    return r;
}

template<bool F32>
__device__ __forceinline__ float ldin(const void* p, size_t i) {
    if (F32) return ((const float*)p)[i];
    else     return b2f(((const bf16*)p)[i]);
}

// ---------------------------------------------------------------------------
// dtype detector (flag: 1 = fp32 inputs, 0 = bf16). R2->R3 evidence: fp32.
// ---------------------------------------------------------------------------
__global__ __launch_bounds__(256) void detect_dtype(const unsigned short* __restrict__ x,
                                                    int* __restrict__ flag)
{
    __shared__ int cnt[256];
    int c = 0;
    for (int i = threadIdx.x; i < 4096; i += 256) {
        const int e = (x[i] >> 7) & 0xFF;
        c += (e >= 100 && e <= 150) ? 1 : 0;
    }
    cnt[threadIdx.x] = c;
    __syncthreads();
    for (int s = 128; s; s >>= 1) {
        if (threadIdx.x < s) cnt[threadIdx.x] += cnt[threadIdx.x + s];
        __syncthreads();
    }
    if (threadIdx.x == 0) *flag = (cnt[0] < 3400) ? 1 : 0;
}

// ---------------------------------------------------------------------------
// prep_bias: 4 bias vectors (512 each) -> fp32 contiguous [4][512]
// ---------------------------------------------------------------------------
__global__ __launch_bounds__(256) void prep_bias(const void* __restrict__ b0,
                                                 const void* __restrict__ b1,
                                                 const void* __restrict__ b2,
                                                 const void* __restrict__ b3,
                                                 float* __restrict__ bias_f,
                                                 const int* __restrict__ flag)
{
    const int idx = blockIdx.x * 256 + threadIdx.x;   // 0..2047
    const int which = idx >> 9, i = idx & 511;
    const void* src = which == 0 ? b0 : (which == 1 ? b1 : (which == 2 ? b2 : b3));
    bias_f[idx] = (*flag) ? ldin<true>(src, i) : ldin<false>(src, i);
}

// ---------------------------------------------------------------------------
// split_x: x[M,512] -> hi/lo bf16 planes (h = bf16(v), l = bf16(v-h))
// ---------------------------------------------------------------------------
__global__ __launch_bounds__(256) void split_x(const void* __restrict__ x,
                                               bf16* __restrict__ xh,
                                               bf16* __restrict__ xl,
                                               const int* __restrict__ flag)
{
    const size_t N = (size_t)BB * LL * DD;
    const size_t i = (size_t)blockIdx.x * 256 + threadIdx.x;
    if (i >= N) return;
    const float v = (*flag) ? ldin<true>(x, i) : ldin<false>(x, i);
    const bf16 h = f2b(v);
    xh[i] = h;
    xl[i] = f2b(v - b2f(h));
}

// ---------------------------------------------------------------------------
// split_w_t: W[512,512] -> transposed hi/lo bf16 planes WT[n][k].
// ---------------------------------------------------------------------------
__global__ __launch_bounds__(256) void split_w_t(const void* __restrict__ W0,
                                                 const void* __restrict__ W1,
                                                 const void* __restrict__ W2,
                                                 const void* __restrict__ W3,
                                                 bf16* __restrict__ WT,
                                                 const int* __restrict__ flag)
{
    const int z = blockIdx.z;
    const void* W = z == 0 ? W0 : (z == 1 ? W1 : (z == 2 ? W2 : W3));
    bf16* Wh = WT + (size_t)z * 524288;
    bf16* Wl = Wh + 262144;
    const int k0 = blockIdx.x * 32, n0 = blockIdx.y * 32;
    const bool f32 = (*flag) != 0;
    __shared__ float Tl[32][33];
    for (int it = 0; it < 4; ++it) {
        const int idx = it * 256 + threadIdx.x;
        const int lk = idx >> 5, ln = idx & 31;
        Tl[lk][ln] = f32 ? ldin<true>(W, (size_t)(k0 + lk) * 512 + n0 + ln)
                         : ldin<false>(W, (size_t)(k0 + lk) * 512 + n0 + ln);
    }
    __syncthreads();
    for (int it = 0; it < 4; ++it) {
        const int idx = it * 256 + threadIdx.x;
        const int ln = idx >> 5, lk = idx & 31;
        const float v = Tl[lk][ln];
        const bf16 h = f2b(v);
        Wh[(size_t)(n0 + ln) * 512 + k0 + lk] = h;
        Wl[(size_t)(n0 + ln) * 512 + k0 + lk] = f2b(v - b2f(h));
    }
}

// ---------------------------------------------------------------------------
// proj_mfma: C(fp32)[16384,512] = (xh+xl) @ (Wh+Wl) + bias. Split-bf16.
// 128x128 block, register-prefetch double buffering.
// ---------------------------------------------------------------------------
__global__ __launch_bounds__(256) void proj_mfma(const bf16* __restrict__ xh,
                                                 const bf16* __restrict__ xl,
                                                 const bf16* __restrict__ WT,
                                                 const float* __restrict__ bias_f,
                                                 float* __restrict__ C0,
                                                 float* __restrict__ C1,
                                                 float* __restrict__ C2)
{
    const int z = blockIdx.z;
    const bf16* Bh = WT + (size_t)z * 524288;
    const bf16* Blo = Bh + 262144;
    float* C = z == 0 ? C0 : (z == 1 ? C1 : C2);
    const float* bias = bias_f + z * 512;

    const int m0 = blockIdx.x * 128, n0 = blockIdx.y * 128;
    const int tid = threadIdx.x, wv = tid >> 6, lane = tid & 63;
    const int wm = (wv >> 1) * 64, wn = (wv & 1) * 64;

    __shared__ __align__(16) bf16 Al[2][128][32];
    __shared__ __align__(16) bf16 Bl[2][128][32];

    f32x4 acc[4][4] = {};
    const int srow = tid >> 2, sq = tid & 3;
    const int mm = lane & 15, cc = lane >> 4;
    const int rpos = (cc ^ ((mm >> 1) & 3)) * 8;

    uint4 pah[2], pal[2], pbh[2], pbl[2];
    #pragma unroll
    for (int p = 0; p < 2; ++p) {
        const int r = p * 64 + srow;
        pah[p] = *(const uint4*)&xh[(size_t)(m0 + r) * 512 + sq * 8];
        pal[p] = *(const uint4*)&xl[(size_t)(m0 + r) * 512 + sq * 8];
        pbh[p] = *(const uint4*)&Bh[(size_t)(n0 + r) * 512 + sq * 8];
        pbl[p] = *(const uint4*)&Blo[(size_t)(n0 + r) * 512 + sq * 8];
    }

    for (int kt = 0; kt < 512; kt += 32) {
        #pragma unroll
        for (int p = 0; p < 2; ++p) {
            const int r = p * 64 + srow;
            const int pos = (sq ^ ((r >> 1) & 3)) * 8;
            *(uint4*)&Al[0][r][pos] = pah[p];
            *(uint4*)&Al[1][r][pos] = pal[p];
            *(uint4*)&Bl[0][r][pos] = pbh[p];
            *(uint4*)&Bl[1][r][pos] = pbl[p];
        }
        __syncthreads();
        if (kt + 32 < 512) {
            #pragma unroll
            for (int p = 0; p < 2; ++p) {
                const int r = p * 64 + srow;
                pah[p] = *(const uint4*)&xh[(size_t)(m0 + r) * 512 + kt + 32 + sq * 8];
                pal[p] = *(const uint4*)&xl[(size_t)(m0 + r) * 512 + kt + 32 + sq * 8];
                pbh[p] = *(const uint4*)&Bh[(size_t)(n0 + r) * 512 + kt + 32 + sq * 8];
                pbl[p] = *(const uint4*)&Blo[(size_t)(n0 + r) * 512 + kt + 32 + sq * 8];
            }
        }

        short8 a_h[4], a_l[4], b_h[4], b_l[4];
        #pragma unroll
        for (int i = 0; i < 4; ++i) {
            a_h[i] = *(const short8*)&Al[0][wm + i * 16 + mm][rpos];
            a_l[i] = *(const short8*)&Al[1][wm + i * 16 + mm][rpos];
            b_h[i] = *(const short8*)&Bl[0][wn + i * 16 + mm][rpos];
            b_l[i] = *(const short8*)&Bl[1][wn + i * 16 + mm][rpos];
        }
        #pragma unroll
        for (int i = 0; i < 4; ++i)
            #pragma unroll
            for (int j = 0; j < 4; ++j) {
                acc[i][j] = MFMA16(a_h[i], b_h[j], acc[i][j]);
                acc[i][j] = MFMA16(a_h[i], b_l[j], acc[i][j]);
                acc[i][j] = MFMA16(a_l[i], b_h[j], acc[i][j]);
            }
        __syncthreads();
    }

    const int nn2 = lane & 15, rq = (lane >> 4) * 4;
    #pragma unroll
    for (int i = 0; i < 4; ++i)
        #pragma unroll
        for (int j = 0; j < 4; ++j) {
            const int col = n0 + wn + j * 16 + nn2;
            const float bv = bias[col];
            #pragma unroll
            for (int r = 0; r < 4; ++r) {
                const int row = m0 + wm + i * 16 + rq + r;
                C[(size_t)row * 512 + col] = acc[i][j][r] + bv;
            }
        }
}

// ---------------------------------------------------------------------------
// out_mfma: out[16384,512] = Ct16(bf16) @ WoT + bias. Plain bf16, prefetch.
// ---------------------------------------------------------------------------
__global__ __launch_bounds__(256) void out_mfma(const bf16* __restrict__ A,
                                                const bf16* __restrict__ BhT,
                                                const float* __restrict__ bias,
                                                void* __restrict__ out,
                                                const int* __restrict__ flag)
{
    const int m0 = blockIdx.x * 128, n0 = blockIdx.y * 128;
    const int tid = threadIdx.x, wv = tid >> 6, lane = tid & 63;
    const int wm = (wv >> 1) * 64, wn = (wv & 1) * 64;

    __shared__ __align__(16) bf16 Al[128][32];
    __shared__ __align__(16) bf16 Bl[128][32];

    f32x4 acc[4][4] = {};
    const int srow = tid >> 2, sq = tid & 3;
    const int mm = lane & 15, cc = lane >> 4;
    const int rpos = (cc ^ ((mm >> 1) & 3)) * 8;

    uint4 pa[2], pb[2];
    #pragma unroll
    for (int p = 0; p < 2; ++p) {
        const int r = p * 64 + srow;
        pa[p] = *(const uint4*)&A[(size_t)(m0 + r) * 512 + sq * 8];
        pb[p] = *(const uint4*)&BhT[(size_t)(n0 + r) * 512 + sq * 8];
    }

    for (int kt = 0; kt < 512; kt += 32) {
        #pragma unroll
        for (int p = 0; p < 2; ++p) {
            const int r = p * 64 + srow;
            const int pos = (sq ^ ((r >> 1) & 3)) * 8;
            *(uint4*)&Al[r][pos] = pa[p];
            *(uint4*)&Bl[r][pos] = pb[p];
        }
        __syncthreads();
        if (kt + 32 < 512) {
            #pragma unroll
            for (int p = 0; p < 2; ++p) {
                const int r = p * 64 + srow;
                pa[p] = *(const uint4*)&A[(size_t)(m0 + r) * 512 + kt + 32 + sq * 8];
                pb[p] = *(const uint4*)&BhT[(size_t)(n0 + r) * 512 + kt + 32 + sq * 8];
            }
        }

        short8 af[4], bfr[4];
        #pragma unroll
        for (int i = 0; i < 4; ++i) {
            af[i]  = *(const short8*)&Al[wm + i * 16 + mm][rpos];
            bfr[i] = *(const short8*)&Bl[wn + i * 16 + mm][rpos];
        }
        #pragma unroll
        for (int i = 0; i < 4; ++i)
            #pragma unroll
            for (int j = 0; j < 4; ++j)
                acc[i][j] = MFMA16(af[i], bfr[j], acc[i][j]);
        __syncthreads();
    }

    const bool f32o = (*flag) != 0;
    const int nn2 = lane & 15, rq = (lane >> 4) * 4;
    #pragma unroll
    for (int i = 0; i < 4; ++i)
        #pragma unroll
        for (int j = 0; j < 4; ++j) {
            const int col = n0 + wn + j * 16 + nn2;
            const float bv = bias[col];
            #pragma unroll
            for (int r = 0; r < 4; ++r) {
                const int row = m0 + wm + i * 16 + rq + r;
                const float v = acc[i][j][r] + bv;
                if (f32o) ((float*)out)[(size_t)row * 512 + col] = v;
                else      ((bf16*)out)[(size_t)row * 512 + col] = f2b(v);
            }
        }
}

// ---------------------------------------------------------------------------
// rfft_cols: packed 2-real-columns-as-one-complex forward FFT (L=2048).
// ---------------------------------------------------------------------------
__global__ __launch_bounds__(256) void rfft_cols(const float* __restrict__ src,
                                                 float2* __restrict__ dst)
{
    const int b = blockIdx.y;
    const int d0 = blockIdx.x * 2;
    __shared__ __align__(16) float2 sh[2][2048];
    __shared__ __align__(16) float2 tw[1024];
    const int tid = threadIdx.x;

    for (int i = tid; i < 1024; i += 256) {
        float s, c;
        __sincosf(-6.283185307179586f * (float)i * (1.0f / 2048.0f), &s, &c);
        tw[i] = make_float2(c, s);
    }
    for (int l = tid; l < 2048; l += 256)
        sh[0][l] = make_float2(src[(size_t)(b * 2048 + l) * 512 + d0],
                               src[(size_t)(b * 2048 + l) * 512 + d0 + 1]);
    __syncthreads();

    int cur = 0, s = 1, ls = 0, tsh = 0;
    for (int nn = 2048; nn > 1; nn >>= 1) {
        const int m = nn >> 1;
        for (int t = tid; t < 1024; t += 256) {
            const int p = t >> ls;
            const int q = t & (s - 1);
            const float2 w  = tw[p << tsh];
            const float2 a  = sh[cur][q + s * p];
            const float2 bb = sh[cur][q + s * (p + m)];
            const float dx = a.x - bb.x, dy = a.y - bb.y;
            sh[cur ^ 1][q + s * 2 * p]       = make_float2(a.x + bb.x, a.y + bb.y);
            sh[cur ^ 1][q + s * (2 * p + 1)] = make_float2(dx * w.x - dy * w.y, dx * w.y + dy * w.x);
        }
        __syncthreads();
        cur ^= 1; s <<= 1; ++ls; ++tsh;
    }
    for (int f = tid; f < FF; f += 256) {
        const float2 Zf = sh[cur][f];
        const float2 Zc = sh[cur][(2048 - f) & 2047];
        const float2 X1 = make_float2(0.5f * (Zf.x + Zc.x), 0.5f * (Zf.y - Zc.y));
        const float wx = Zf.x - Zc.x, wy = Zf.y + Zc.y;
        const float2 X2 = make_float2(0.5f * wy, -0.5f * wx);
        dst[(size_t)(b * FF + f) * 512 + d0]     = X1;
        dst[(size_t)(b * FF + f) * 512 + d0 + 1] = X2;
    }
}

// ---------------------------------------------------------------------------
// irfft_cols: packed 2-column inverse; writes bf16 time-domain.
// ---------------------------------------------------------------------------
__global__ __launch_bounds__(256) void irfft_cols(const float2* __restrict__ Cf,
                                                  bf16* __restrict__ Ct16)
{
    const int b = blockIdx.y;
    const int d0 = blockIdx.x * 2;
    __shared__ __align__(16) float2 sh[2][2048];
    __shared__ __align__(16) float2 tw[1024];
    const int tid = threadIdx.x;

    for (int i = tid; i < 1024; i += 256) {
        float s, c;
        __sincosf(-6.283185307179586f * (float)i * (1.0f / 2048.0f), &s, &c);
        tw[i] = make_float2(c, s);
    }
    for (int f = tid; f < FF; f += 256) {
        float2 c1 = Cf[(size_t)(b * FF + f) * 512 + d0];
        float2 c2 = Cf[(size_t)(b * FF + f) * 512 + d0 + 1];
        if (f == 0 || f == 1024) { c1.y = 0.f; c2.y = 0.f; }
        sh[0][f] = make_float2(c1.x - c2.y, c1.y + c2.x);
        if (f >= 1 && f <= 1023)
            sh[0][2048 - f] = make_float2(c1.x + c2.y, -c1.y + c2.x);
    }
    __syncthreads();

    int cur = 0, s = 1, ls = 0, tsh = 0;
    for (int nn = 2048; nn > 1; nn >>= 1) {
        const int m = nn >> 1;
        for (int t = tid; t < 1024; t += 256) {
            const int p = t >> ls;
            const int q = t & (s - 1);
            const float2 wv = tw[p << tsh];
            const float2 w = make_float2(wv.x, -wv.y);
            const float2 a  = sh[cur][q + s * p];
            const float2 bb = sh[cur][q + s * (p + m)];
            const float dx = a.x - bb.x, dy = a.y - bb.y;
            sh[cur ^ 1][q + s * 2 * p]       = make_float2(a.x + bb.x, a.y + bb.y);
            sh[cur ^ 1][q + s * (2 * p + 1)] = make_float2(dx * w.x - dy * w.y, dx * w.y + dy * w.x);
        }
        __syncthreads();
        cur ^= 1; s <<= 1; ++ls; ++tsh;
    }
    for (int l = tid; l < 2048; l += 256) {
        const float2 z = sh[cur][l];
        Ct16[(size_t)(b * 2048 + l) * 512 + d0]     = f2b(z.x * (1.0f / 2048.0f));
        Ct16[(size_t)(b * 2048 + l) * 512 + d0 + 1] = f2b(z.y * (1.0f / 2048.0f));
    }
}

// ---------------------------------------------------------------------------
// split_qk: freq float2 -> 4 bf16 planes (re_hi | re_lo | im_hi | im_lo)
// ---------------------------------------------------------------------------
__global__ __launch_bounds__(256) void split_qk(const float2* __restrict__ src,
                                                bf16* __restrict__ dst)
{
    const size_t SP = (size_t)BB * FF * DD;
    const size_t i = (size_t)blockIdx.x * 256 + threadIdx.x;
    if (i >= SP) return;
    const float2 v = src[i];
    const bf16 h0 = f2b(v.x);
    const bf16 h1 = f2b(v.y);
    dst[i]          = h0;
    dst[i + SP]     = f2b(v.x - b2f(h0));
    dst[i + 2 * SP] = h1;
    dst[i + 3 * SP] = f2b(v.y - b2f(h1));
}

// ---------------------------------------------------------------------------
// att_mfma v3: 128f x 64g block, XCD-swizzled flat grid, register prefetch.
// flat&7 -> xcd owns batch b=xcd; f-rows in groups of 3 x 17 g-tiles
// so the A-band stays L2-resident per XCD (4MB L2/XCD).
// ---------------------------------------------------------------------------
__global__ __launch_bounds__(256, 2) void att_mfma(const bf16* __restrict__ Asp,
                                                   const bf16* __restrict__ Bsp,
                                                   float* __restrict__ att)
{
    const size_t SP = (size_t)BB * FF * DD;
    const int flat = blockIdx.x;
    const int b    = flat & 7;
    const int slot = flat >> 3;          // 0..152
    const int grp  = slot / 51;          // 0..2
    const int rem  = slot % 51;
    const int g    = rem / 3;            // 0..16
    const int r3   = rem % 3;
    const int ft   = grp * 3 + r3;       // 0..8
    const int f0 = ft * 128, g0 = g * 64;

    const int tid = threadIdx.x;
    const int wv = tid >> 6, lane = tid & 63;
    const int wvf = wv >> 1, wvg = wv & 1;

    __shared__ __align__(16) bf16 Al[4][128][32];   // 32 KB
    __shared__ __align__(16) bf16 Bl[4][64][32];    // 16 KB

    f32x4 accr[4][2] = {}; f32x4 acci[4][2] = {};

    const int srow = tid >> 2, sq = tid & 3;
    const int r16 = lane & 15, cc = lane >> 4;
    const int rpos = (cc ^ ((r16 >> 1) & 3)) * 8;
    const size_t abase = (size_t)(b * FF + f0) * 512;
    const size_t bbase = (size_t)(b * FF + g0) * 512;

    uint4 pa[2][4], pb[4];
    #pragma unroll
    for (int p = 0; p < 2; ++p)
        #pragma unroll
        for (int pl = 0; pl < 4; ++pl)
            pa[p][pl] = *(const uint4*)&Asp[(size_t)pl * SP + abase +
                                            (size_t)(p * 64 + srow) * 512 + sq * 8];
    #pragma unroll
    for (int pl = 0; pl < 4; ++pl)
        pb[pl] = *(const uint4*)&Bsp[(size_t)pl * SP + bbase + (size_t)srow * 512 + sq * 8];

    for (int kt = 0; kt < 512; kt += 32) {
        #pragma unroll
        for (int p = 0; p < 2; ++p) {
            const int row = p * 64 + srow;
            const int pos = (sq ^ ((row >> 1) & 3)) * 8;
            #pragma unroll
            for (int pl = 0; pl < 4; ++pl)
                *(uint4*)&Al[pl][row][pos] = pa[p][pl];
        }
        {
            const int pos = (sq ^ ((srow >> 1) & 3)) * 8;
            #pragma unroll
            for (int pl = 0; pl < 4; ++pl)
                *(uint4*)&Bl[pl][srow][pos] = pb[pl];
        }
        __syncthreads();
        if (kt + 32 < 512) {
            #pragma unroll
            for (int p = 0; p < 2; ++p)
                #pragma unroll
                for (int pl = 0; pl < 4; ++pl)
                    pa[p][pl] = *(const uint4*)&Asp[(size_t)pl * SP + abase +
                                                    (size_t)(p * 64 + srow) * 512 + kt + 32 + sq * 8];
            #pragma unroll
            for (int pl = 0; pl < 4; ++pl)
                pb[pl] = *(const uint4*)&Bsp[(size_t)pl * SP + bbase +
                                             (size_t)srow * 512 + kt + 32 + sq * 8];
        }

        short8 aA[4][4], bB[2][4], nb[2][2];
        #pragma unroll
        for (int i = 0; i < 4; ++i) {
            const int row = wvf * 64 + i * 16 + r16;
            #pragma unroll
            for (int pl = 0; pl < 4; ++pl)
                aA[i][pl] = *(const short8*)&Al[pl][row][rpos];
        }
        #pragma unroll
        for (int j = 0; j < 2; ++j) {
            const int row = wvg * 32 + j * 16 + r16;
            #pragma unroll
            for (int pl = 0; pl < 4; ++pl)
                bB[j][pl] = *(const short8*)&Bl[pl][row][rpos];
            nb[j][0] = neg8(bB[j][2]);
            nb[j][1] = neg8(bB[j][3]);
        }
        // planes: 0=re_hi 1=re_lo 2=im_hi 3=im_lo
        #pragma unroll
        for (int i = 0; i < 4; ++i)
            #pragma unroll
            for (int j = 0; j < 2; ++j) {
                accr[i][j] = MFMA16(aA[i][0], bB[j][0], accr[i][j]);
                accr[i][j] = MFMA16(aA[i][0], bB[j][1], accr[i][j]);
                accr[i][j] = MFMA16(aA[i][1], bB[j][0], accr[i][j]);
                accr[i][j] = MFMA16(aA[i][2], nb[j][0], accr[i][j]);
                accr[i][j] = MFMA16(aA[i][2], nb[j][1], accr[i][j]);
                accr[i][j] = MFMA16(aA[i][3], nb[j][0], accr[i][j]);
                acci[i][j] = MFMA16(aA[i][0], bB[j][2], acci[i][j]);
                acci[i][j] = MFMA16(aA[i][0], bB[j][3], acci[i][j]);
                acci[i][j] = MFMA16(aA[i][1], bB[j][2], acci[i][j]);
                acci[i][j] = MFMA16(aA[i][2], bB[j][0], acci[i][j]);
                acci[i][j] = MFMA16(aA[i][2], bB[j][1], acci[i][j]);
                acci[i][j] = MFMA16(aA[i][3], bB[j][0], acci[i][j]);
            }
        __syncthreads();
    }

    const int rq = (lane >> 4) * 4;
    #pragma unroll
    for (int i = 0; i < 4; ++i)
        #pragma unroll
        for (int j = 0; j < 2; ++j)
            #pragma unroll
            for (int r = 0; r < 4; ++r) {
                const int f = f0 + wvf * 64 + i * 16 + rq + r;
                const int gg = g0 + wvg * 32 + j * 16 + r16;
                if (f < FF && gg < FF) {
                    const float ar = accr[i][j][r];
                    const float ai = acci[i][j][r];
                    att[((size_t)(b * FF + f)) * FF + gg] = ATT_SCALE * sqrtf(ar * ar + ai * ai);
                }
            }
}

// ---------------------------------------------------------------------------
// softmax over g per (b,f) row; fp32 in place + bf16 copy padded to GP.
// ---------------------------------------------------------------------------
__global__ __launch_bounds__(256) void softmax_rows(float* __restrict__ att,
                                                    bf16* __restrict__ att16)
{
    const int row = blockIdx.x;
    float* p = att + (size_t)row * FF;
    bf16* q = att16 + (size_t)row * GP;
    const int tid = threadIdx.x;
    const int lane = tid & 63, wid = tid >> 6;
    __shared__ float red[4];

    float m = -1e30f;
    for (int i = tid; i < FF; i += 256) m = fmaxf(m, p[i]);
    #pragma unroll
    for (int o = 32; o; o >>= 1) m = fmaxf(m, __shfl_down(m, o));
    if (lane == 0) red[wid] = m;
    __syncthreads();
    m = fmaxf(fmaxf(red[0], red[1]), fmaxf(red[2], red[3]));
    __syncthreads();

    float s = 0.f;
    for (int i = tid; i < FF; i += 256) { const float e = expf(p[i] - m); p[i] = e; s += e; }
    #pragma unroll
    for (int o = 32; o; o >>= 1) s += __shfl_down(s, o);
    if (lane == 0) red[wid] = s;
    __syncthreads();
    s = red[0] + red[1] + red[2] + red[3];
    const float inv = 1.f / s;
    for (int i = tid; i < GP; i += 256) {
        if (i < FF) {
            const float v = p[i] * inv;
            p[i] = v;
            q[i] = f2b(v);
        } else {
            q[i] = f2b(0.f);
        }
    }
}

// ---------------------------------------------------------------------------
// transpose V: Vf[b,g,d] float2 -> Vct[b,n,g] bf16 (n<512 re, else im).
// ---------------------------------------------------------------------------
__global__ __launch_bounds__(256) void transpose_v(const float2* __restrict__ Vf,
                                                   bf16* __restrict__ Vct)
{
    const int b = blockIdx.z;
    const int d0 = blockIdx.x * 32;
    const int g0 = blockIdx.y * 32;
    __shared__ float2 Tl[32][33];
    const int tid = threadIdx.x;

    for (int k = 0; k < 4; ++k) {
        const int idx = k * 256 + tid;
        const int lg = idx >> 5, ld = idx & 31;
        const int g = g0 + lg;
        Tl[lg][ld] = (g < FF) ? Vf[((size_t)(b * FF + g)) * 512 + d0 + ld]
                              : make_float2(0.f, 0.f);
    }
    __syncthreads();
    for (int k = 0; k < 4; ++k) {
        const int idx = k * 256 + tid;
        const int ld = idx >> 5, lg = idx & 31;
        const float2 v = Tl[lg][ld];
        Vct[((size_t)(b * 1024 + d0 + ld)) * GP + g0 + lg]       = f2b(v.x);
        Vct[((size_t)(b * 1024 + 512 + d0 + ld)) * GP + g0 + lg] = f2b(v.y);
    }
}

// ---------------------------------------------------------------------------
// ctx_mfma v2: 128f x 128n block, XCD swizzle, register prefetch.
// Cf[b,f,d] = sum_g attn * Vf (bf16 MFMA, K=GP).
// ---------------------------------------------------------------------------
__global__ __launch_bounds__(256) void ctx_mfma(const bf16* __restrict__ att16,
                                                const bf16* __restrict__ Vct,
                                                float* __restrict__ Cf)
{
    const int flat = blockIdx.x;          // 576 blocks
    const int b    = flat & 7;
    const int slot = flat >> 3;           // 0..71
    const int grp  = slot / 24;           // 0..2
    const int rem  = slot % 24;
    const int nt   = rem / 3;             // 0..7
    const int r3   = rem % 3;
    const int ft   = grp * 3 + r3;        // 0..8
    const int f0 = ft * 128, n0 = nt * 128;

    const int tid = threadIdx.x;
    const int wv = tid >> 6, lane = tid & 63;
    const int wm = (wv >> 1) * 64, wn = (wv & 1) * 64;

    __shared__ __align__(16) bf16 Al[128][32];
    __shared__ __align__(16) bf16 Bl[128][32];

    f32x4 acc[4][4] = {};
    const int srow = tid >> 2, sq = tid & 3;
    const int mm = lane & 15, cc = lane >> 4;
    const int rpos = (cc ^ ((mm >> 1) & 3)) * 8;

    uint4 pa[2], pb[2];
    #pragma unroll
    for (int p = 0; p < 2; ++p) {
        const int r = p * 64 + srow;
        pa[p] = *(const uint4*)&att16[((size_t)(b * FF + f0 + r)) * GP + sq * 8];
        pb[p] = *(const uint4*)&Vct[((size_t)(b * 1024 + n0 + r)) * GP + sq * 8];
    }

    for (int kt = 0; kt < GP; kt += 32) {
        #pragma unroll
        for (int p = 0; p < 2; ++p) {
            const int r = p * 64 + srow;
            const int pos = (sq ^ ((r >> 1) & 3)) * 8;
            *(uint4*)&Al[r][pos] = pa[p];
            *(uint4*)&Bl[r][pos] = pb[p];
        }
        __syncthreads();
        if (kt + 32 < GP) {
            #pragma unroll
            for (int p = 0; p < 2; ++p) {
                const int r = p * 64 + srow;
                pa[p] = *(const uint4*)&att16[((size_t)(b * FF + f0 + r)) * GP + kt + 32 + sq * 8];
                pb[p] = *(const uint4*)&Vct[((size_t)(b * 1024 + n0 + r)) * GP + kt + 32 + sq * 8];
            }
        }

        short8 af[4], bfr[4];
        #pragma unroll
        for (int i = 0; i < 4; ++i) {
            af[i]  = *(const short8*)&Al[wm + i * 16 + mm][rpos];
            bfr[i] = *(const short8*)&Bl[wn + i * 16 + mm][rpos];
        }
        #pragma unroll
        for (int i = 0; i < 4; ++i)
            #pragma unroll
            for (int j = 0; j < 4; ++j)
                acc[i][j] = MFMA16(af[i], bfr[j], acc[i][j]);
        __syncthreads();
    }

    const int nn = lane & 15, rq = (lane >> 4) * 4;
    #pragma unroll
    for (int i = 0; i < 4; ++i)
        #pragma unroll
        for (int j = 0; j < 4; ++j)
            #pragma unroll
            for (int r = 0; r < 4; ++r) {
                const int f = f0 + wm + i * 16 + rq + r;
                const int n = n0 + wn + j * 16 + nn;
                if (f < FF) {
                    const int d = n & 511, im = n >> 9;
                    Cf[(((size_t)(b * FF + f)) * 512 + d) * 2 + im] = acc[i][j][r];
                }
            }
}

// ---------------------------------------------------------------------------
// launch — 4x33.65MB slots + 4MB weight region + bias + flag (~138.8 MB)
// ---------------------------------------------------------------------------
extern "C" void kernel_launch(void* const* d_in, const int* in_sizes, int n_in,
                              void* d_out, int out_size, void* d_ws, size_t ws_size,
                              hipStream_t stream)
{
    const void* x  = d_in[0];
    const void* Wq = d_in[1]; const void* bq = d_in[2];
    const void* Wk = d_in[3]; const void* bk = d_in[4];
    const void* Wv = d_in[5]; const void* bv = d_in[6];
    const void* Wo = d_in[7]; const void* bo = d_in[8];

    const size_t SLOT = 33652736;
    char* ws = (char*)d_ws;
    char* s0 = ws;               char* s1 = ws + SLOT;
    char* s2 = ws + 2 * SLOT;    char* s3 = ws + 3 * SLOT;
    char* wreg = ws + 4 * SLOT;
    bf16*  WT     = (bf16*)wreg;
    float* bias_f = (float*)(wreg + 4194304);
    int*   flag   = (int*)(wreg + 4194304 + 8192);

    bf16*   xh   = (bf16*)s3;
    bf16*   xl   = (bf16*)(s3 + 16777216);
    float*  Qt   = (float*)s0;  float* Kt = (float*)s1;  float* Vt = (float*)s2;
    float2* Qf   = (float2*)s3;
    bf16*   Asp  = (bf16*)s0;
    float2* Kf   = (float2*)s3;
    bf16*   Bsp  = (bf16*)s1;
    float2* Vf   = (float2*)s3;
    bf16*   Vct  = (bf16*)s2;
    float*  attn = (float*)s3;
    bf16*   att16= (bf16*)s0;
    float2* Cf   = (float2*)s1;
    bf16*   Ct16 = (bf16*)s2;

    const int SPLITQ_BLOCKS = (int)(((size_t)BB * FF * DD + 255) / 256);
    const int SPLITX_BLOCKS = (int)(((size_t)BB * LL * DD + 255) / 256);

    detect_dtype<<<1, 256, 0, stream>>>((const unsigned short*)x, flag);
    prep_bias<<<8, 256, 0, stream>>>(bq, bk, bv, bo, bias_f, flag);
    split_x<<<SPLITX_BLOCKS, 256, 0, stream>>>(x, xh, xl, flag);
    split_w_t<<<dim3(16, 16, 4), 256, 0, stream>>>(Wq, Wk, Wv, Wo, WT, flag);
    proj_mfma<<<dim3(128, 4, 3), 256, 0, stream>>>(xh, xl, WT, bias_f, Qt, Kt, Vt);
    rfft_cols<<<dim3(256, 8), 256, 0, stream>>>(Qt, Qf);
    split_qk<<<SPLITQ_BLOCKS, 256, 0, stream>>>(Qf, Asp);
    rfft_cols<<<dim3(256, 8), 256, 0, stream>>>(Kt, Kf);
    split_qk<<<SPLITQ_BLOCKS, 256, 0, stream>>>(Kf, Bsp);
    rfft_cols<<<dim3(256, 8), 256, 0, stream>>>(Vt, Vf);
    transpose_v<<<dim3(16, 33, 8), 256, 0, stream>>>(Vf, Vct);
    att_mfma<<<dim3(1224), 256, 0, stream>>>(Asp, Bsp, attn);
    softmax_rows<<<dim3(BB * FF), 256, 0, stream>>>(attn, att16);
    ctx_mfma<<<dim3(576), 256, 0, stream>>>(att16, Vct, (float*)Cf);
    irfft_cols<<<dim3(256, 8), 256, 0, stream>>>(Cf, Ct16);
    out_mfma<<<dim3(128, 4), 256, 0, stream>>>(Ct16, WT + 3 * 524288, bias_f + 3 * 512,
                                               d_out, flag);
}

// Round 8
// 726.570 us; speedup vs baseline: 1.6418x; 1.6418x over previous
//
#include <hip/hip_runtime.h>
#include <hip/hip_bf16.h>
#include <math.h>

typedef __hip_bfloat16 bf16;
typedef __attribute__((ext_vector_type(8))) short short8;
typedef __attribute__((ext_vector_type(4))) float f32x4;

#define BB 8
#define LL 2048
#define DD 512
#define FF 1025   // LL/2+1
#define GP 1056   // g padded to 33*32 for ctx K-chunks
#define ATT_SCALE 0.04419417382415922f   // 512^-0.5

__device__ __forceinline__ float b2f(bf16 v) { return __bfloat162float(v); }
__device__ __forceinline__ bf16  f2b(float v) { return __float2bfloat16(v); }

#define MFMA16(a, b, c) __builtin_amdgcn_mfma_f32_16x16x32_bf16((a), (b), (c), 0, 0, 0)

// exact bf16 negation of an 8-element fragment (sign-bit flip)
__device__ __forceinline__ short8 neg8(short8 v) {
    short8 r;
    #pragma unroll
    for (int t = 0; t < 8; ++t) r[t] = (short)(v[t] ^ (short)0x8000);
    return r;
}

template<bool F32>
__device__ __forceinline__ float ldin(const void* p, size_t i) {
    if (F32) return ((const float*)p)[i];
    else     return b2f(((const bf16*)p)[i]);
}

// ---------------------------------------------------------------------------
// dtype detector (flag: 1 = fp32 inputs, 0 = bf16). R2->R3 evidence: fp32.
// ---------------------------------------------------------------------------
__global__ __launch_bounds__(256) void detect_dtype(const unsigned short* __restrict__ x,
                                                    int* __restrict__ flag)
{
    __shared__ int cnt[256];
    int c = 0;
    for (int i = threadIdx.x; i < 4096; i += 256) {
        const int e = (x[i] >> 7) & 0xFF;
        c += (e >= 100 && e <= 150) ? 1 : 0;
    }
    cnt[threadIdx.x] = c;
    __syncthreads();
    for (int s = 128; s; s >>= 1) {
        if (threadIdx.x < s) cnt[threadIdx.x] += cnt[threadIdx.x + s];
        __syncthreads();
    }
    if (threadIdx.x == 0) *flag = (cnt[0] < 3400) ? 1 : 0;
}

// ---------------------------------------------------------------------------
// prep_bias: 4 bias vectors (512 each) -> fp32 contiguous [4][512]
// ---------------------------------------------------------------------------
__global__ __launch_bounds__(256) void prep_bias(const void* __restrict__ b0,
                                                 const void* __restrict__ b1,
                                                 const void* __restrict__ b2,
                                                 const void* __restrict__ b3,
                                                 float* __restrict__ bias_f,
                                                 const int* __restrict__ flag)
{
    const int idx = blockIdx.x * 256 + threadIdx.x;   // 0..2047
    const int which = idx >> 9, i = idx & 511;
    const void* src = which == 0 ? b0 : (which == 1 ? b1 : (which == 2 ? b2 : b3));
    bias_f[idx] = (*flag) ? ldin<true>(src, i) : ldin<false>(src, i);
}

// ---------------------------------------------------------------------------
// split_x: x[M,512] -> hi/lo bf16 planes (h = bf16(v), l = bf16(v-h))
// ---------------------------------------------------------------------------
__global__ __launch_bounds__(256) void split_x(const void* __restrict__ x,
                                               bf16* __restrict__ xh,
                                               bf16* __restrict__ xl,
                                               const int* __restrict__ flag)
{
    const size_t N = (size_t)BB * LL * DD;
    const size_t i = (size_t)blockIdx.x * 256 + threadIdx.x;
    if (i >= N) return;
    const float v = (*flag) ? ldin<true>(x, i) : ldin<false>(x, i);
    const bf16 h = f2b(v);
    xh[i] = h;
    xl[i] = f2b(v - b2f(h));
}

// ---------------------------------------------------------------------------
// split_w_t: W[512,512] -> transposed hi/lo bf16 planes WT[n][k].
// ---------------------------------------------------------------------------
__global__ __launch_bounds__(256) void split_w_t(const void* __restrict__ W0,
                                                 const void* __restrict__ W1,
                                                 const void* __restrict__ W2,
                                                 const void* __restrict__ W3,
                                                 bf16* __restrict__ WT,
                                                 const int* __restrict__ flag)
{
    const int z = blockIdx.z;
    const void* W = z == 0 ? W0 : (z == 1 ? W1 : (z == 2 ? W2 : W3));
    bf16* Wh = WT + (size_t)z * 524288;
    bf16* Wl = Wh + 262144;
    const int k0 = blockIdx.x * 32, n0 = blockIdx.y * 32;
    const bool f32 = (*flag) != 0;
    __shared__ float Tl[32][33];
    for (int it = 0; it < 4; ++it) {
        const int idx = it * 256 + threadIdx.x;
        const int lk = idx >> 5, ln = idx & 31;
        Tl[lk][ln] = f32 ? ldin<true>(W, (size_t)(k0 + lk) * 512 + n0 + ln)
                         : ldin<false>(W, (size_t)(k0 + lk) * 512 + n0 + ln);
    }
    __syncthreads();
    for (int it = 0; it < 4; ++it) {
        const int idx = it * 256 + threadIdx.x;
        const int ln = idx >> 5, lk = idx & 31;
        const float v = Tl[lk][ln];
        const bf16 h = f2b(v);
        Wh[(size_t)(n0 + ln) * 512 + k0 + lk] = h;
        Wl[(size_t)(n0 + ln) * 512 + k0 + lk] = f2b(v - b2f(h));
    }
}

// ---------------------------------------------------------------------------
// proj_mfma: C(fp32)[16384,512] = (xh+xl) @ (Wh+Wl) + bias. Split-bf16.
// 128x128 block, 4 waves (2x2 of 64x64), BK=32. XOR-swizzled LDS (stride 32).
// NO register prefetch (R7 lesson: spills — 880MB scratch writes).
// ---------------------------------------------------------------------------
__global__ __launch_bounds__(256) void proj_mfma(const bf16* __restrict__ xh,
                                                 const bf16* __restrict__ xl,
                                                 const bf16* __restrict__ WT,
                                                 const float* __restrict__ bias_f,
                                                 float* __restrict__ C0,
                                                 float* __restrict__ C1,
                                                 float* __restrict__ C2)
{
    const int z = blockIdx.z;
    const bf16* Bh = WT + (size_t)z * 524288;
    const bf16* Blo = Bh + 262144;
    float* C = z == 0 ? C0 : (z == 1 ? C1 : C2);
    const float* bias = bias_f + z * 512;

    const int m0 = blockIdx.x * 128, n0 = blockIdx.y * 128;
    const int tid = threadIdx.x, wv = tid >> 6, lane = tid & 63;
    const int wm = (wv >> 1) * 64, wn = (wv & 1) * 64;

    __shared__ __align__(16) bf16 Al[2][128][32];
    __shared__ __align__(16) bf16 Bl[2][128][32];

    f32x4 acc[4][4] = {};
    const int srow = tid >> 2, sq = tid & 3;
    const int mm = lane & 15, cc = lane >> 4;
    const int rpos = (cc ^ ((mm >> 1) & 3)) * 8;

    for (int kt = 0; kt < 512; kt += 32) {
        #pragma unroll
        for (int p = 0; p < 2; ++p) {
            const int r = p * 64 + srow;
            const int pos = (sq ^ ((r >> 1) & 3)) * 8;
            *(uint4*)&Al[0][r][pos] = *(const uint4*)&xh[(size_t)(m0 + r) * 512 + kt + sq * 8];
            *(uint4*)&Al[1][r][pos] = *(const uint4*)&xl[(size_t)(m0 + r) * 512 + kt + sq * 8];
            *(uint4*)&Bl[0][r][pos] = *(const uint4*)&Bh[(size_t)(n0 + r) * 512 + kt + sq * 8];
            *(uint4*)&Bl[1][r][pos] = *(const uint4*)&Blo[(size_t)(n0 + r) * 512 + kt + sq * 8];
        }
        __syncthreads();

        short8 a_h[4], a_l[4], b_h[4], b_l[4];
        #pragma unroll
        for (int i = 0; i < 4; ++i) {
            a_h[i] = *(const short8*)&Al[0][wm + i * 16 + mm][rpos];
            a_l[i] = *(const short8*)&Al[1][wm + i * 16 + mm][rpos];
            b_h[i] = *(const short8*)&Bl[0][wn + i * 16 + mm][rpos];
            b_l[i] = *(const short8*)&Bl[1][wn + i * 16 + mm][rpos];
        }
        #pragma unroll
        for (int i = 0; i < 4; ++i)
            #pragma unroll
            for (int j = 0; j < 4; ++j) {
                acc[i][j] = MFMA16(a_h[i], b_h[j], acc[i][j]);
                acc[i][j] = MFMA16(a_h[i], b_l[j], acc[i][j]);
                acc[i][j] = MFMA16(a_l[i], b_h[j], acc[i][j]);
            }
        __syncthreads();
    }

    const int nn2 = lane & 15, rq = (lane >> 4) * 4;
    #pragma unroll
    for (int i = 0; i < 4; ++i)
        #pragma unroll
        for (int j = 0; j < 4; ++j) {
            const int col = n0 + wn + j * 16 + nn2;
            const float bv = bias[col];
            #pragma unroll
            for (int r = 0; r < 4; ++r) {
                const int row = m0 + wm + i * 16 + rq + r;
                C[(size_t)row * 512 + col] = acc[i][j][r] + bv;
            }
        }
}

// ---------------------------------------------------------------------------
// out_mfma: out[16384,512] = Ct16(bf16) @ WoT + bias. Plain bf16, swizzled.
// ---------------------------------------------------------------------------
__global__ __launch_bounds__(256) void out_mfma(const bf16* __restrict__ A,
                                                const bf16* __restrict__ BhT,
                                                const float* __restrict__ bias,
                                                void* __restrict__ out,
                                                const int* __restrict__ flag)
{
    const int m0 = blockIdx.x * 128, n0 = blockIdx.y * 128;
    const int tid = threadIdx.x, wv = tid >> 6, lane = tid & 63;
    const int wm = (wv >> 1) * 64, wn = (wv & 1) * 64;

    __shared__ __align__(16) bf16 Al[128][32];
    __shared__ __align__(16) bf16 Bl[128][32];

    f32x4 acc[4][4] = {};
    const int srow = tid >> 2, sq = tid & 3;
    const int mm = lane & 15, cc = lane >> 4;
    const int rpos = (cc ^ ((mm >> 1) & 3)) * 8;

    for (int kt = 0; kt < 512; kt += 32) {
        #pragma unroll
        for (int p = 0; p < 2; ++p) {
            const int r = p * 64 + srow;
            const int pos = (sq ^ ((r >> 1) & 3)) * 8;
            *(uint4*)&Al[r][pos] = *(const uint4*)&A[(size_t)(m0 + r) * 512 + kt + sq * 8];
            *(uint4*)&Bl[r][pos] = *(const uint4*)&BhT[(size_t)(n0 + r) * 512 + kt + sq * 8];
        }
        __syncthreads();

        short8 af[4], bfr[4];
        #pragma unroll
        for (int i = 0; i < 4; ++i) {
            af[i]  = *(const short8*)&Al[wm + i * 16 + mm][rpos];
            bfr[i] = *(const short8*)&Bl[wn + i * 16 + mm][rpos];
        }
        #pragma unroll
        for (int i = 0; i < 4; ++i)
            #pragma unroll
            for (int j = 0; j < 4; ++j)
                acc[i][j] = MFMA16(af[i], bfr[j], acc[i][j]);
        __syncthreads();
    }

    const bool f32o = (*flag) != 0;
    const int nn2 = lane & 15, rq = (lane >> 4) * 4;
    #pragma unroll
    for (int i = 0; i < 4; ++i)
        #pragma unroll
        for (int j = 0; j < 4; ++j) {
            const int col = n0 + wn + j * 16 + nn2;
            const float bv = bias[col];
            #pragma unroll
            for (int r = 0; r < 4; ++r) {
                const int row = m0 + wm + i * 16 + rq + r;
                const float v = acc[i][j][r] + bv;
                if (f32o) ((float*)out)[(size_t)row * 512 + col] = v;
                else      ((bf16*)out)[(size_t)row * 512 + col] = f2b(v);
            }
        }
}

// ---------------------------------------------------------------------------
// rfft_cols: packed 2-real-columns-as-one-complex forward FFT (L=2048).
// ---------------------------------------------------------------------------
__global__ __launch_bounds__(256) void rfft_cols(const float* __restrict__ src,
                                                 float2* __restrict__ dst)
{
    const int b = blockIdx.y;
    const int d0 = blockIdx.x * 2;
    __shared__ __align__(16) float2 sh[2][2048];
    __shared__ __align__(16) float2 tw[1024];
    const int tid = threadIdx.x;

    for (int i = tid; i < 1024; i += 256) {
        float s, c;
        __sincosf(-6.283185307179586f * (float)i * (1.0f / 2048.0f), &s, &c);
        tw[i] = make_float2(c, s);
    }
    for (int l = tid; l < 2048; l += 256)
        sh[0][l] = make_float2(src[(size_t)(b * 2048 + l) * 512 + d0],
                               src[(size_t)(b * 2048 + l) * 512 + d0 + 1]);
    __syncthreads();

    int cur = 0, s = 1, ls = 0, tsh = 0;
    for (int nn = 2048; nn > 1; nn >>= 1) {
        const int m = nn >> 1;
        for (int t = tid; t < 1024; t += 256) {
            const int p = t >> ls;
            const int q = t & (s - 1);
            const float2 w  = tw[p << tsh];
            const float2 a  = sh[cur][q + s * p];
            const float2 bb = sh[cur][q + s * (p + m)];
            const float dx = a.x - bb.x, dy = a.y - bb.y;
            sh[cur ^ 1][q + s * 2 * p]       = make_float2(a.x + bb.x, a.y + bb.y);
            sh[cur ^ 1][q + s * (2 * p + 1)] = make_float2(dx * w.x - dy * w.y, dx * w.y + dy * w.x);
        }
        __syncthreads();
        cur ^= 1; s <<= 1; ++ls; ++tsh;
    }
    for (int f = tid; f < FF; f += 256) {
        const float2 Zf = sh[cur][f];
        const float2 Zc = sh[cur][(2048 - f) & 2047];
        const float2 X1 = make_float2(0.5f * (Zf.x + Zc.x), 0.5f * (Zf.y - Zc.y));
        const float wx = Zf.x - Zc.x, wy = Zf.y + Zc.y;
        const float2 X2 = make_float2(0.5f * wy, -0.5f * wx);
        dst[(size_t)(b * FF + f) * 512 + d0]     = X1;
        dst[(size_t)(b * FF + f) * 512 + d0 + 1] = X2;
    }
}

// ---------------------------------------------------------------------------
// irfft_cols: packed 2-column inverse; writes bf16 time-domain.
// ---------------------------------------------------------------------------
__global__ __launch_bounds__(256) void irfft_cols(const float2* __restrict__ Cf,
                                                  bf16* __restrict__ Ct16)
{
    const int b = blockIdx.y;
    const int d0 = blockIdx.x * 2;
    __shared__ __align__(16) float2 sh[2][2048];
    __shared__ __align__(16) float2 tw[1024];
    const int tid = threadIdx.x;

    for (int i = tid; i < 1024; i += 256) {
        float s, c;
        __sincosf(-6.283185307179586f * (float)i * (1.0f / 2048.0f), &s, &c);
        tw[i] = make_float2(c, s);
    }
    for (int f = tid; f < FF; f += 256) {
        float2 c1 = Cf[(size_t)(b * FF + f) * 512 + d0];
        float2 c2 = Cf[(size_t)(b * FF + f) * 512 + d0 + 1];
        if (f == 0 || f == 1024) { c1.y = 0.f; c2.y = 0.f; }
        sh[0][f] = make_float2(c1.x - c2.y, c1.y + c2.x);
        if (f >= 1 && f <= 1023)
            sh[0][2048 - f] = make_float2(c1.x + c2.y, -c1.y + c2.x);
    }
    __syncthreads();

    int cur = 0, s = 1, ls = 0, tsh = 0;
    for (int nn = 2048; nn > 1; nn >>= 1) {
        const int m = nn >> 1;
        for (int t = tid; t < 1024; t += 256) {
            const int p = t >> ls;
            const int q = t & (s - 1);
            const float2 wv = tw[p << tsh];
            const float2 w = make_float2(wv.x, -wv.y);
            const float2 a  = sh[cur][q + s * p];
            const float2 bb = sh[cur][q + s * (p + m)];
            const float dx = a.x - bb.x, dy = a.y - bb.y;
            sh[cur ^ 1][q + s * 2 * p]       = make_float2(a.x + bb.x, a.y + bb.y);
            sh[cur ^ 1][q + s * (2 * p + 1)] = make_float2(dx * w.x - dy * w.y, dx * w.y + dy * w.x);
        }
        __syncthreads();
        cur ^= 1; s <<= 1; ++ls; ++tsh;
    }
    for (int l = tid; l < 2048; l += 256) {
        const float2 z = sh[cur][l];
        Ct16[(size_t)(b * 2048 + l) * 512 + d0]     = f2b(z.x * (1.0f / 2048.0f));
        Ct16[(size_t)(b * 2048 + l) * 512 + d0 + 1] = f2b(z.y * (1.0f / 2048.0f));
    }
}

// ---------------------------------------------------------------------------
// split_qk: freq float2 -> 4 bf16 planes (re_hi | re_lo | im_hi | im_lo)
// ---------------------------------------------------------------------------
__global__ __launch_bounds__(256) void split_qk(const float2* __restrict__ src,
                                                bf16* __restrict__ dst)
{
    const size_t SP = (size_t)BB * FF * DD;
    const size_t i = (size_t)blockIdx.x * 256 + threadIdx.x;
    if (i >= SP) return;
    const float2 v = src[i];
    const bf16 h0 = f2b(v.x);
    const bf16 h1 = f2b(v.y);
    dst[i]          = h0;
    dst[i + SP]     = f2b(v.x - b2f(h0));
    dst[i + 2 * SP] = h1;
    dst[i + 3 * SP] = f2b(v.y - b2f(h1));
}

// ---------------------------------------------------------------------------
// att_mfma v4: R6 body (no register prefetch — R7 spilled) + XCD-swizzled
// flat grid: b = flat&7 (one batch per XCD slot), f-tiles in groups of 3
// x 17 g-tiles so the 128f A-band (~3x2MB) stays L2-resident per XCD.
// ---------------------------------------------------------------------------
__global__ __launch_bounds__(256, 2) void att_mfma(const bf16* __restrict__ Asp,
                                                   const bf16* __restrict__ Bsp,
                                                   float* __restrict__ att)
{
    const size_t SP = (size_t)BB * FF * DD;
    const int flat = blockIdx.x;
    const int b    = flat & 7;
    const int slot = flat >> 3;          // 0..152
    const int grp  = slot / 51;          // 0..2
    const int rem  = slot % 51;
    const int g    = rem / 3;            // 0..16
    const int r3   = rem % 3;
    const int ft   = grp * 3 + r3;       // 0..8
    const int f0 = ft * 128, g0 = g * 64;

    const int tid = threadIdx.x;
    const int wv = tid >> 6, lane = tid & 63;
    const int wvf = wv >> 1, wvg = wv & 1;

    __shared__ __align__(16) bf16 Al[4][128][32];   // 32 KB
    __shared__ __align__(16) bf16 Bl[4][64][32];    // 16 KB

    f32x4 accr[4][2] = {}; f32x4 acci[4][2] = {};

    const int srow = tid >> 2, sq = tid & 3;
    const int r16 = lane & 15, cc = lane >> 4;
    const int rpos = (cc ^ ((r16 >> 1) & 3)) * 8;
    const size_t abase = (size_t)(b * FF + f0) * 512;
    const size_t bbase = (size_t)(b * FF + g0) * 512;

    for (int kt = 0; kt < 512; kt += 32) {
        #pragma unroll
        for (int p = 0; p < 2; ++p) {
            const int row = p * 64 + srow;
            const int pos = (sq ^ ((row >> 1) & 3)) * 8;
            #pragma unroll
            for (int pl = 0; pl < 4; ++pl)
                *(uint4*)&Al[pl][row][pos] =
                    *(const uint4*)&Asp[(size_t)pl * SP + abase + (size_t)row * 512 + kt + sq * 8];
        }
        {
            const int pos = (sq ^ ((srow >> 1) & 3)) * 8;
            #pragma unroll
            for (int pl = 0; pl < 4; ++pl)
                *(uint4*)&Bl[pl][srow][pos] =
                    *(const uint4*)&Bsp[(size_t)pl * SP + bbase + (size_t)srow * 512 + kt + sq * 8];
        }
        __syncthreads();

        short8 aA[4][4], bB[2][4], nb[2][2];
        #pragma unroll
        for (int i = 0; i < 4; ++i) {
            const int row = wvf * 64 + i * 16 + r16;
            #pragma unroll
            for (int pl = 0; pl < 4; ++pl)
                aA[i][pl] = *(const short8*)&Al[pl][row][rpos];
        }
        #pragma unroll
        for (int j = 0; j < 2; ++j) {
            const int row = wvg * 32 + j * 16 + r16;
            #pragma unroll
            for (int pl = 0; pl < 4; ++pl)
                bB[j][pl] = *(const short8*)&Bl[pl][row][rpos];
            nb[j][0] = neg8(bB[j][2]);
            nb[j][1] = neg8(bB[j][3]);
        }
        // planes: 0=re_hi 1=re_lo 2=im_hi 3=im_lo
        #pragma unroll
        for (int i = 0; i < 4; ++i)
            #pragma unroll
            for (int j = 0; j < 2; ++j) {
                accr[i][j] = MFMA16(aA[i][0], bB[j][0], accr[i][j]);
                accr[i][j] = MFMA16(aA[i][0], bB[j][1], accr[i][j]);
                accr[i][j] = MFMA16(aA[i][1], bB[j][0], accr[i][j]);
                accr[i][j] = MFMA16(aA[i][2], nb[j][0], accr[i][j]);
                accr[i][j] = MFMA16(aA[i][2], nb[j][1], accr[i][j]);
                accr[i][j] = MFMA16(aA[i][3], nb[j][0], accr[i][j]);
                acci[i][j] = MFMA16(aA[i][0], bB[j][2], acci[i][j]);
                acci[i][j] = MFMA16(aA[i][0], bB[j][3], acci[i][j]);
                acci[i][j] = MFMA16(aA[i][1], bB[j][2], acci[i][j]);
                acci[i][j] = MFMA16(aA[i][2], bB[j][0], acci[i][j]);
                acci[i][j] = MFMA16(aA[i][2], bB[j][1], acci[i][j]);
                acci[i][j] = MFMA16(aA[i][3], bB[j][0], acci[i][j]);
            }
        __syncthreads();
    }

    const int rq = (lane >> 4) * 4;
    #pragma unroll
    for (int i = 0; i < 4; ++i)
        #pragma unroll
        for (int j = 0; j < 2; ++j)
            #pragma unroll
            for (int r = 0; r < 4; ++r) {
                const int f = f0 + wvf * 64 + i * 16 + rq + r;
                const int gg = g0 + wvg * 32 + j * 16 + r16;
                if (f < FF && gg < FF) {
                    const float ar = accr[i][j][r];
                    const float ai = acci[i][j][r];
                    att[((size_t)(b * FF + f)) * FF + gg] = ATT_SCALE * sqrtf(ar * ar + ai * ai);
                }
            }
}

// ---------------------------------------------------------------------------
// softmax over g per (b,f) row; fp32 in place + bf16 copy padded to GP.
// ---------------------------------------------------------------------------
__global__ __launch_bounds__(256) void softmax_rows(float* __restrict__ att,
                                                    bf16* __restrict__ att16)
{
    const int row = blockIdx.x;
    float* p = att + (size_t)row * FF;
    bf16* q = att16 + (size_t)row * GP;
    const int tid = threadIdx.x;
    const int lane = tid & 63, wid = tid >> 6;
    __shared__ float red[4];

    float m = -1e30f;
    for (int i = tid; i < FF; i += 256) m = fmaxf(m, p[i]);
    #pragma unroll
    for (int o = 32; o; o >>= 1) m = fmaxf(m, __shfl_down(m, o));
    if (lane == 0) red[wid] = m;
    __syncthreads();
    m = fmaxf(fmaxf(red[0], red[1]), fmaxf(red[2], red[3]));
    __syncthreads();

    float s = 0.f;
    for (int i = tid; i < FF; i += 256) { const float e = expf(p[i] - m); p[i] = e; s += e; }
    #pragma unroll
    for (int o = 32; o; o >>= 1) s += __shfl_down(s, o);
    if (lane == 0) red[wid] = s;
    __syncthreads();
    s = red[0] + red[1] + red[2] + red[3];
    const float inv = 1.f / s;
    for (int i = tid; i < GP; i += 256) {
        if (i < FF) {
            const float v = p[i] * inv;
            p[i] = v;
            q[i] = f2b(v);
        } else {
            q[i] = f2b(0.f);
        }
    }
}

// ---------------------------------------------------------------------------
// transpose V: Vf[b,g,d] float2 -> Vct[b,n,g] bf16 (n<512 re, else im).
// ---------------------------------------------------------------------------
__global__ __launch_bounds__(256) void transpose_v(const float2* __restrict__ Vf,
                                                   bf16* __restrict__ Vct)
{
    const int b = blockIdx.z;
    const int d0 = blockIdx.x * 32;
    const int g0 = blockIdx.y * 32;
    __shared__ float2 Tl[32][33];
    const int tid = threadIdx.x;

    for (int k = 0; k < 4; ++k) {
        const int idx = k * 256 + tid;
        const int lg = idx >> 5, ld = idx & 31;
        const int g = g0 + lg;
        Tl[lg][ld] = (g < FF) ? Vf[((size_t)(b * FF + g)) * 512 + d0 + ld]
                              : make_float2(0.f, 0.f);
    }
    __syncthreads();
    for (int k = 0; k < 4; ++k) {
        const int idx = k * 256 + tid;
        const int ld = idx >> 5, lg = idx & 31;
        const float2 v = Tl[lg][ld];
        Vct[((size_t)(b * 1024 + d0 + ld)) * GP + g0 + lg]       = f2b(v.x);
        Vct[((size_t)(b * 1024 + 512 + d0 + ld)) * GP + g0 + lg] = f2b(v.y);
    }
}

// ---------------------------------------------------------------------------
// ctx_mfma (R6-proven 64x64 form): Cf[b,f,d] = sum_g attn * Vf.
// ---------------------------------------------------------------------------
__global__ __launch_bounds__(256) void ctx_mfma(const bf16* __restrict__ att16,
                                                const bf16* __restrict__ Vct,
                                                float* __restrict__ Cf)
{
    const int b = blockIdx.z;
    const int f0 = blockIdx.x * 64, n0 = blockIdx.y * 64;
    const int tid = threadIdx.x;
    const int wv = tid >> 6, lane = tid & 63;
    const int wf = (wv >> 1) * 32, wn = (wv & 1) * 32;

    __shared__ __align__(16) bf16 Al[64][32];
    __shared__ __align__(16) bf16 Bl[64][32];

    f32x4 acc[2][2] = {};
    const int srow = tid >> 2, sq = tid & 3;
    const int m = lane & 15, cc = lane >> 4;
    const int rpos = (cc ^ ((m >> 1) & 3)) * 8;
    const int spos = (sq ^ ((srow >> 1) & 3)) * 8;

    for (int kt = 0; kt < GP; kt += 32) {
        uint4 av = make_uint4(0, 0, 0, 0);
        if (f0 + srow < FF)
            av = *(const uint4*)&att16[((size_t)(b * FF + f0 + srow)) * GP + kt + sq * 8];
        *(uint4*)&Al[srow][spos] = av;
        *(uint4*)&Bl[srow][spos] =
            *(const uint4*)&Vct[((size_t)(b * 1024 + n0 + srow)) * GP + kt + sq * 8];
        __syncthreads();

        short8 af[2], bfr[2];
        #pragma unroll
        for (int s = 0; s < 2; ++s) {
            af[s]  = *(const short8*)&Al[wf + s * 16 + m][rpos];
            bfr[s] = *(const short8*)&Bl[wn + s * 16 + m][rpos];
        }
        #pragma unroll
        for (int i = 0; i < 2; ++i)
            #pragma unroll
            for (int j = 0; j < 2; ++j)
                acc[i][j] = MFMA16(af[i], bfr[j], acc[i][j]);
        __syncthreads();
    }

    const int nn = lane & 15, rq = (lane >> 4) * 4;
    #pragma unroll
    for (int i = 0; i < 2; ++i)
        #pragma unroll
        for (int j = 0; j < 2; ++j)
            #pragma unroll
            for (int r = 0; r < 4; ++r) {
                const int f = f0 + wf + i * 16 + rq + r;
                const int n = n0 + wn + j * 16 + nn;
                if (f < FF) {
                    const int d = n & 511, im = n >> 9;
                    Cf[(((size_t)(b * FF + f)) * 512 + d) * 2 + im] = acc[i][j][r];
                }
            }
}

// ---------------------------------------------------------------------------
// launch — 4x33.65MB slots + 4MB weight region + bias + flag (~138.8 MB)
// ---------------------------------------------------------------------------
extern "C" void kernel_launch(void* const* d_in, const int* in_sizes, int n_in,
                              void* d_out, int out_size, void* d_ws, size_t ws_size,
                              hipStream_t stream)
{
    const void* x  = d_in[0];
    const void* Wq = d_in[1]; const void* bq = d_in[2];
    const void* Wk = d_in[3]; const void* bk = d_in[4];
    const void* Wv = d_in[5]; const void* bv = d_in[6];
    const void* Wo = d_in[7]; const void* bo = d_in[8];

    const size_t SLOT = 33652736;
    char* ws = (char*)d_ws;
    char* s0 = ws;               char* s1 = ws + SLOT;
    char* s2 = ws + 2 * SLOT;    char* s3 = ws + 3 * SLOT;
    char* wreg = ws + 4 * SLOT;
    bf16*  WT     = (bf16*)wreg;
    float* bias_f = (float*)(wreg + 4194304);
    int*   flag   = (int*)(wreg + 4194304 + 8192);

    bf16*   xh   = (bf16*)s3;
    bf16*   xl   = (bf16*)(s3 + 16777216);
    float*  Qt   = (float*)s0;  float* Kt = (float*)s1;  float* Vt = (float*)s2;
    float2* Qf   = (float2*)s3;
    bf16*   Asp  = (bf16*)s0;
    float2* Kf   = (float2*)s3;
    bf16*   Bsp  = (bf16*)s1;
    float2* Vf   = (float2*)s3;
    bf16*   Vct  = (bf16*)s2;
    float*  attn = (float*)s3;
    bf16*   att16= (bf16*)s0;
    float2* Cf   = (float2*)s1;
    bf16*   Ct16 = (bf16*)s2;

    const int SPLITQ_BLOCKS = (int)(((size_t)BB * FF * DD + 255) / 256);
    const int SPLITX_BLOCKS = (int)(((size_t)BB * LL * DD + 255) / 256);

    detect_dtype<<<1, 256, 0, stream>>>((const unsigned short*)x, flag);
    prep_bias<<<8, 256, 0, stream>>>(bq, bk, bv, bo, bias_f, flag);
    split_x<<<SPLITX_BLOCKS, 256, 0, stream>>>(x, xh, xl, flag);
    split_w_t<<<dim3(16, 16, 4), 256, 0, stream>>>(Wq, Wk, Wv, Wo, WT, flag);
    proj_mfma<<<dim3(128, 4, 3), 256, 0, stream>>>(xh, xl, WT, bias_f, Qt, Kt, Vt);
    rfft_cols<<<dim3(256, 8), 256, 0, stream>>>(Qt, Qf);
    split_qk<<<SPLITQ_BLOCKS, 256, 0, stream>>>(Qf, Asp);
    rfft_cols<<<dim3(256, 8), 256, 0, stream>>>(Kt, Kf);
    split_qk<<<SPLITQ_BLOCKS, 256, 0, stream>>>(Kf, Bsp);
    rfft_cols<<<dim3(256, 8), 256, 0, stream>>>(Vt, Vf);
    transpose_v<<<dim3(16, 33, 8), 256, 0, stream>>>(Vf, Vct);
    att_mfma<<<dim3(1224), 256, 0, stream>>>(Asp, Bsp, attn);
    softmax_rows<<<dim3(BB * FF), 256, 0, stream>>>(attn, att16);
    ctx_mfma<<<dim3(17, 16, 8), 256, 0, stream>>>(att16, Vct, (float*)Cf);
    irfft_cols<<<dim3(256, 8), 256, 0, stream>>>(Cf, Ct16);
    out_mfma<<<dim3(128, 4), 256, 0, stream>>>(Ct16, WT + 3 * 524288, bias_f + 3 * 512,
                                               d_out, flag);
}

// Round 9
// 641.447 us; speedup vs baseline: 1.8597x; 1.1327x over previous
//
#include <hip/hip_runtime.h>
#include <hip/hip_bf16.h>
#include <math.h>

typedef __hip_bfloat16 bf16;
typedef __attribute__((ext_vector_type(8))) short short8;
typedef __attribute__((ext_vector_type(4))) float f32x4;

#define BB 8
#define LL 2048
#define DD 512
#define FF 1025   // LL/2+1
#define GP 1056   // g padded to 33*32 for ctx K-chunks
#define ATT_SCALE 0.04419417382415922f   // 512^-0.5

__device__ __forceinline__ float b2f(bf16 v) { return __bfloat162float(v); }
__device__ __forceinline__ bf16  f2b(float v) { return __float2bfloat16(v); }

#define MFMA16(a, b, c) __builtin_amdgcn_mfma_f32_16x16x32_bf16((a), (b), (c), 0, 0, 0)

// exact bf16 negation of an 8-element fragment (sign-bit flip)
__device__ __forceinline__ short8 neg8(short8 v) {
    short8 r;
    #pragma unroll
    for (int t = 0; t < 8; ++t) r[t] = (short)(v[t] ^ (short)0x8000);
    return r;
}

template<bool F32>
__device__ __forceinline__ float ldin(const void* p, size_t i) {
    if (F32) return ((const float*)p)[i];
    else     return b2f(((const bf16*)p)[i]);
}

// ---------------------------------------------------------------------------
// dtype detector (flag: 1 = fp32 inputs, 0 = bf16). R2->R3 evidence: fp32.
// ---------------------------------------------------------------------------
__global__ __launch_bounds__(256) void detect_dtype(const unsigned short* __restrict__ x,
                                                    int* __restrict__ flag)
{
    __shared__ int cnt[256];
    int c = 0;
    for (int i = threadIdx.x; i < 4096; i += 256) {
        const int e = (x[i] >> 7) & 0xFF;
        c += (e >= 100 && e <= 150) ? 1 : 0;
    }
    cnt[threadIdx.x] = c;
    __syncthreads();
    for (int s = 128; s; s >>= 1) {
        if (threadIdx.x < s) cnt[threadIdx.x] += cnt[threadIdx.x + s];
        __syncthreads();
    }
    if (threadIdx.x == 0) *flag = (cnt[0] < 3400) ? 1 : 0;
}

// ---------------------------------------------------------------------------
// prep_bias: 4 bias vectors (512 each) -> fp32 contiguous [4][512]
// ---------------------------------------------------------------------------
__global__ __launch_bounds__(256) void prep_bias(const void* __restrict__ b0,
                                                 const void* __restrict__ b1,
                                                 const void* __restrict__ b2,
                                                 const void* __restrict__ b3,
                                                 float* __restrict__ bias_f,
                                                 const int* __restrict__ flag)
{
    const int idx = blockIdx.x * 256 + threadIdx.x;   // 0..2047
    const int which = idx >> 9, i = idx & 511;
    const void* src = which == 0 ? b0 : (which == 1 ? b1 : (which == 2 ? b2 : b3));
    bias_f[idx] = (*flag) ? ldin<true>(src, i) : ldin<false>(src, i);
}

// ---------------------------------------------------------------------------
// split_x: x[M,512] -> hi/lo bf16 planes (h = bf16(v), l = bf16(v-h))
// ---------------------------------------------------------------------------
__global__ __launch_bounds__(256) void split_x(const void* __restrict__ x,
                                               bf16* __restrict__ xh,
                                               bf16* __restrict__ xl,
                                               const int* __restrict__ flag)
{
    const size_t N = (size_t)BB * LL * DD;
    const size_t i = (size_t)blockIdx.x * 256 + threadIdx.x;
    if (i >= N) return;
    const float v = (*flag) ? ldin<true>(x, i) : ldin<false>(x, i);
    const bf16 h = f2b(v);
    xh[i] = h;
    xl[i] = f2b(v - b2f(h));
}

// ---------------------------------------------------------------------------
// split_w_t: W[512,512] -> transposed hi/lo bf16 planes WT[n][k].
// ---------------------------------------------------------------------------
__global__ __launch_bounds__(256) void split_w_t(const void* __restrict__ W0,
                                                 const void* __restrict__ W1,
                                                 const void* __restrict__ W2,
                                                 const void* __restrict__ W3,
                                                 bf16* __restrict__ WT,
                                                 const int* __restrict__ flag)
{
    const int z = blockIdx.z;
    const void* W = z == 0 ? W0 : (z == 1 ? W1 : (z == 2 ? W2 : W3));
    bf16* Wh = WT + (size_t)z * 524288;
    bf16* Wl = Wh + 262144;
    const int k0 = blockIdx.x * 32, n0 = blockIdx.y * 32;
    const bool f32 = (*flag) != 0;
    __shared__ float Tl[32][33];
    for (int it = 0; it < 4; ++it) {
        const int idx = it * 256 + threadIdx.x;
        const int lk = idx >> 5, ln = idx & 31;
        Tl[lk][ln] = f32 ? ldin<true>(W, (size_t)(k0 + lk) * 512 + n0 + ln)
                         : ldin<false>(W, (size_t)(k0 + lk) * 512 + n0 + ln);
    }
    __syncthreads();
    for (int it = 0; it < 4; ++it) {
        const int idx = it * 256 + threadIdx.x;
        const int ln = idx >> 5, lk = idx & 31;
        const float v = Tl[lk][ln];
        const bf16 h = f2b(v);
        Wh[(size_t)(n0 + ln) * 512 + k0 + lk] = h;
        Wl[(size_t)(n0 + ln) * 512 + k0 + lk] = f2b(v - b2f(h));
    }
}

// ---------------------------------------------------------------------------
// proj_mfma: C(fp32)[16384,512] = (xh+xl) @ (Wh+Wl) + bias. Split-bf16.
// 128x128 block, 4 waves (2x2 of 64x64), BK=32. XOR-swizzled LDS (stride 32).
// NO register prefetch (R7 lesson: spills — 880MB scratch writes).
// ---------------------------------------------------------------------------
__global__ __launch_bounds__(256) void proj_mfma(const bf16* __restrict__ xh,
                                                 const bf16* __restrict__ xl,
                                                 const bf16* __restrict__ WT,
                                                 const float* __restrict__ bias_f,
                                                 float* __restrict__ C0,
                                                 float* __restrict__ C1,
                                                 float* __restrict__ C2)
{
    const int z = blockIdx.z;
    const bf16* Bh = WT + (size_t)z * 524288;
    const bf16* Blo = Bh + 262144;
    float* C = z == 0 ? C0 : (z == 1 ? C1 : C2);
    const float* bias = bias_f + z * 512;

    const int m0 = blockIdx.x * 128, n0 = blockIdx.y * 128;
    const int tid = threadIdx.x, wv = tid >> 6, lane = tid & 63;
    const int wm = (wv >> 1) * 64, wn = (wv & 1) * 64;

    __shared__ __align__(16) bf16 Al[2][128][32];
    __shared__ __align__(16) bf16 Bl[2][128][32];

    f32x4 acc[4][4] = {};
    const int srow = tid >> 2, sq = tid & 3;
    const int mm = lane & 15, cc = lane >> 4;
    const int rpos = (cc ^ ((mm >> 1) & 3)) * 8;

    for (int kt = 0; kt < 512; kt += 32) {
        #pragma unroll
        for (int p = 0; p < 2; ++p) {
            const int r = p * 64 + srow;
            const int pos = (sq ^ ((r >> 1) & 3)) * 8;
            *(uint4*)&Al[0][r][pos] = *(const uint4*)&xh[(size_t)(m0 + r) * 512 + kt + sq * 8];
            *(uint4*)&Al[1][r][pos] = *(const uint4*)&xl[(size_t)(m0 + r) * 512 + kt + sq * 8];
            *(uint4*)&Bl[0][r][pos] = *(const uint4*)&Bh[(size_t)(n0 + r) * 512 + kt + sq * 8];
            *(uint4*)&Bl[1][r][pos] = *(const uint4*)&Blo[(size_t)(n0 + r) * 512 + kt + sq * 8];
        }
        __syncthreads();

        short8 a_h[4], a_l[4], b_h[4], b_l[4];
        #pragma unroll
        for (int i = 0; i < 4; ++i) {
            a_h[i] = *(const short8*)&Al[0][wm + i * 16 + mm][rpos];
            a_l[i] = *(const short8*)&Al[1][wm + i * 16 + mm][rpos];
            b_h[i] = *(const short8*)&Bl[0][wn + i * 16 + mm][rpos];
            b_l[i] = *(const short8*)&Bl[1][wn + i * 16 + mm][rpos];
        }
        #pragma unroll
        for (int i = 0; i < 4; ++i)
            #pragma unroll
            for (int j = 0; j < 4; ++j) {
                acc[i][j] = MFMA16(a_h[i], b_h[j], acc[i][j]);
                acc[i][j] = MFMA16(a_h[i], b_l[j], acc[i][j]);
                acc[i][j] = MFMA16(a_l[i], b_h[j], acc[i][j]);
            }
        __syncthreads();
    }

    const int nn2 = lane & 15, rq = (lane >> 4) * 4;
    #pragma unroll
    for (int i = 0; i < 4; ++i)
        #pragma unroll
        for (int j = 0; j < 4; ++j) {
            const int col = n0 + wn + j * 16 + nn2;
            const float bv = bias[col];
            #pragma unroll
            for (int r = 0; r < 4; ++r) {
                const int row = m0 + wm + i * 16 + rq + r;
                C[(size_t)row * 512 + col] = acc[i][j][r] + bv;
            }
        }
}

// ---------------------------------------------------------------------------
// out_mfma: out[16384,512] = Ct16(bf16) @ WoT + bias. Plain bf16, swizzled.
// ---------------------------------------------------------------------------
__global__ __launch_bounds__(256) void out_mfma(const bf16* __restrict__ A,
                                                const bf16* __restrict__ BhT,
                                                const float* __restrict__ bias,
                                                void* __restrict__ out,
                                                const int* __restrict__ flag)
{
    const int m0 = blockIdx.x * 128, n0 = blockIdx.y * 128;
    const int tid = threadIdx.x, wv = tid >> 6, lane = tid & 63;
    const int wm = (wv >> 1) * 64, wn = (wv & 1) * 64;

    __shared__ __align__(16) bf16 Al[128][32];
    __shared__ __align__(16) bf16 Bl[128][32];

    f32x4 acc[4][4] = {};
    const int srow = tid >> 2, sq = tid & 3;
    const int mm = lane & 15, cc = lane >> 4;
    const int rpos = (cc ^ ((mm >> 1) & 3)) * 8;

    for (int kt = 0; kt < 512; kt += 32) {
        #pragma unroll
        for (int p = 0; p < 2; ++p) {
            const int r = p * 64 + srow;
            const int pos = (sq ^ ((r >> 1) & 3)) * 8;
            *(uint4*)&Al[r][pos] = *(const uint4*)&A[(size_t)(m0 + r) * 512 + kt + sq * 8];
            *(uint4*)&Bl[r][pos] = *(const uint4*)&BhT[(size_t)(n0 + r) * 512 + kt + sq * 8];
        }
        __syncthreads();

        short8 af[4], bfr[4];
        #pragma unroll
        for (int i = 0; i < 4; ++i) {
            af[i]  = *(const short8*)&Al[wm + i * 16 + mm][rpos];
            bfr[i] = *(const short8*)&Bl[wn + i * 16 + mm][rpos];
        }
        #pragma unroll
        for (int i = 0; i < 4; ++i)
            #pragma unroll
            for (int j = 0; j < 4; ++j)
                acc[i][j] = MFMA16(af[i], bfr[j], acc[i][j]);
        __syncthreads();
    }

    const bool f32o = (*flag) != 0;
    const int nn2 = lane & 15, rq = (lane >> 4) * 4;
    #pragma unroll
    for (int i = 0; i < 4; ++i)
        #pragma unroll
        for (int j = 0; j < 4; ++j) {
            const int col = n0 + wn + j * 16 + nn2;
            const float bv = bias[col];
            #pragma unroll
            for (int r = 0; r < 4; ++r) {
                const int row = m0 + wm + i * 16 + rq + r;
                const float v = acc[i][j][r] + bv;
                if (f32o) ((float*)out)[(size_t)row * 512 + col] = v;
                else      ((bf16*)out)[(size_t)row * 512 + col] = f2b(v);
            }
        }
}

// ---------------------------------------------------------------------------
// rfft_cols: packed 2-real-columns-as-one-complex forward FFT (L=2048).
// ---------------------------------------------------------------------------
__global__ __launch_bounds__(256) void rfft_cols(const float* __restrict__ src,
                                                 float2* __restrict__ dst)
{
    const int b = blockIdx.y;
    const int d0 = blockIdx.x * 2;
    __shared__ __align__(16) float2 sh[2][2048];
    __shared__ __align__(16) float2 tw[1024];
    const int tid = threadIdx.x;

    for (int i = tid; i < 1024; i += 256) {
        float s, c;
        __sincosf(-6.283185307179586f * (float)i * (1.0f / 2048.0f), &s, &c);
        tw[i] = make_float2(c, s);
    }
    for (int l = tid; l < 2048; l += 256)
        sh[0][l] = make_float2(src[(size_t)(b * 2048 + l) * 512 + d0],
                               src[(size_t)(b * 2048 + l) * 512 + d0 + 1]);
    __syncthreads();

    int cur = 0, s = 1, ls = 0, tsh = 0;
    for (int nn = 2048; nn > 1; nn >>= 1) {
        const int m = nn >> 1;
        for (int t = tid; t < 1024; t += 256) {
            const int p = t >> ls;
            const int q = t & (s - 1);
            const float2 w  = tw[p << tsh];
            const float2 a  = sh[cur][q + s * p];
            const float2 bb = sh[cur][q + s * (p + m)];
            const float dx = a.x - bb.x, dy = a.y - bb.y;
            sh[cur ^ 1][q + s * 2 * p]       = make_float2(a.x + bb.x, a.y + bb.y);
            sh[cur ^ 1][q + s * (2 * p + 1)] = make_float2(dx * w.x - dy * w.y, dx * w.y + dy * w.x);
        }
        __syncthreads();
        cur ^= 1; s <<= 1; ++ls; ++tsh;
    }
    for (int f = tid; f < FF; f += 256) {
        const float2 Zf = sh[cur][f];
        const float2 Zc = sh[cur][(2048 - f) & 2047];
        const float2 X1 = make_float2(0.5f * (Zf.x + Zc.x), 0.5f * (Zf.y - Zc.y));
        const float wx = Zf.x - Zc.x, wy = Zf.y + Zc.y;
        const float2 X2 = make_float2(0.5f * wy, -0.5f * wx);
        dst[(size_t)(b * FF + f) * 512 + d0]     = X1;
        dst[(size_t)(b * FF + f) * 512 + d0 + 1] = X2;
    }
}

// ---------------------------------------------------------------------------
// irfft_cols: packed 2-column inverse; writes bf16 time-domain.
// ---------------------------------------------------------------------------
__global__ __launch_bounds__(256) void irfft_cols(const float2* __restrict__ Cf,
                                                  bf16* __restrict__ Ct16)
{
    const int b = blockIdx.y;
    const int d0 = blockIdx.x * 2;
    __shared__ __align__(16) float2 sh[2][2048];
    __shared__ __align__(16) float2 tw[1024];
    const int tid = threadIdx.x;

    for (int i = tid; i < 1024; i += 256) {
        float s, c;
        __sincosf(-6.283185307179586f * (float)i * (1.0f / 2048.0f), &s, &c);
        tw[i] = make_float2(c, s);
    }
    for (int f = tid; f < FF; f += 256) {
        float2 c1 = Cf[(size_t)(b * FF + f) * 512 + d0];
        float2 c2 = Cf[(size_t)(b * FF + f) * 512 + d0 + 1];
        if (f == 0 || f == 1024) { c1.y = 0.f; c2.y = 0.f; }
        sh[0][f] = make_float2(c1.x - c2.y, c1.y + c2.x);
        if (f >= 1 && f <= 1023)
            sh[0][2048 - f] = make_float2(c1.x + c2.y, -c1.y + c2.x);
    }
    __syncthreads();

    int cur = 0, s = 1, ls = 0, tsh = 0;
    for (int nn = 2048; nn > 1; nn >>= 1) {
        const int m = nn >> 1;
        for (int t = tid; t < 1024; t += 256) {
            const int p = t >> ls;
            const int q = t & (s - 1);
            const float2 wv = tw[p << tsh];
            const float2 w = make_float2(wv.x, -wv.y);
            const float2 a  = sh[cur][q + s * p];
            const float2 bb = sh[cur][q + s * (p + m)];
            const float dx = a.x - bb.x, dy = a.y - bb.y;
            sh[cur ^ 1][q + s * 2 * p]       = make_float2(a.x + bb.x, a.y + bb.y);
            sh[cur ^ 1][q + s * (2 * p + 1)] = make_float2(dx * w.x - dy * w.y, dx * w.y + dy * w.x);
        }
        __syncthreads();
        cur ^= 1; s <<= 1; ++ls; ++tsh;
    }
    for (int l = tid; l < 2048; l += 256) {
        const float2 z = sh[cur][l];
        Ct16[(size_t)(b * 2048 + l) * 512 + d0]     = f2b(z.x * (1.0f / 2048.0f));
        Ct16[(size_t)(b * 2048 + l) * 512 + d0 + 1] = f2b(z.y * (1.0f / 2048.0f));
    }
}

// ---------------------------------------------------------------------------
// conv_qk: freq float2 -> 2 bf16 planes (re | im). Plain bf16 QK (R8 lesson:
// att is LDS/MFMA-issue-bound; split-bf16's 3x MFMA + 2x LDS not worth it —
// logit noise ~0.6 post-scale vs top-gap ~290).
// ---------------------------------------------------------------------------
__global__ __launch_bounds__(256) void conv_qk(const float2* __restrict__ src,
                                               bf16* __restrict__ dst)
{
    const size_t SP = (size_t)BB * FF * DD;
    const size_t i = (size_t)blockIdx.x * 256 + threadIdx.x;
    if (i >= SP) return;
    const float2 v = src[i];
    dst[i]      = f2b(v.x);
    dst[i + SP] = f2b(v.y);
}

// ---------------------------------------------------------------------------
// att_mfma v5: plain bf16, 2 planes. 128f x 64g block, 4 waves (2f x 2g),
// wave 64f x 32g (4x2 subtiles). 4 MFMAs per subtile pair (sign-flip).
// XCD-swizzled flat grid (R8-proven). LDS 24 KB -> 3+ blocks/CU.
// ---------------------------------------------------------------------------
__global__ __launch_bounds__(256, 2) void att_mfma(const bf16* __restrict__ Asp,
                                                   const bf16* __restrict__ Bsp,
                                                   float* __restrict__ att)
{
    const size_t SP = (size_t)BB * FF * DD;
    const int flat = blockIdx.x;
    const int b    = flat & 7;
    const int slot = flat >> 3;          // 0..152
    const int grp  = slot / 51;          // 0..2
    const int rem  = slot % 51;
    const int g    = rem / 3;            // 0..16
    const int r3   = rem % 3;
    const int ft   = grp * 3 + r3;       // 0..8
    const int f0 = ft * 128, g0 = g * 64;

    const int tid = threadIdx.x;
    const int wv = tid >> 6, lane = tid & 63;
    const int wvf = wv >> 1, wvg = wv & 1;

    __shared__ __align__(16) bf16 Al[2][128][32];   // 16 KB
    __shared__ __align__(16) bf16 Bl[2][64][32];    //  8 KB

    f32x4 accr[4][2] = {}; f32x4 acci[4][2] = {};

    const int srow = tid >> 2, sq = tid & 3;
    const int r16 = lane & 15, cc = lane >> 4;
    const int rpos = (cc ^ ((r16 >> 1) & 3)) * 8;
    const size_t abase = (size_t)(b * FF + f0) * 512;
    const size_t bbase = (size_t)(b * FF + g0) * 512;

    for (int kt = 0; kt < 512; kt += 32) {
        #pragma unroll
        for (int p = 0; p < 2; ++p) {
            const int row = p * 64 + srow;
            const int pos = (sq ^ ((row >> 1) & 3)) * 8;
            #pragma unroll
            for (int pl = 0; pl < 2; ++pl)
                *(uint4*)&Al[pl][row][pos] =
                    *(const uint4*)&Asp[(size_t)pl * SP + abase + (size_t)row * 512 + kt + sq * 8];
        }
        {
            const int pos = (sq ^ ((srow >> 1) & 3)) * 8;
            #pragma unroll
            for (int pl = 0; pl < 2; ++pl)
                *(uint4*)&Bl[pl][srow][pos] =
                    *(const uint4*)&Bsp[(size_t)pl * SP + bbase + (size_t)srow * 512 + kt + sq * 8];
        }
        __syncthreads();

        short8 aA[4][2], bB[2][2], nb[2];
        #pragma unroll
        for (int i = 0; i < 4; ++i) {
            const int row = wvf * 64 + i * 16 + r16;
            #pragma unroll
            for (int pl = 0; pl < 2; ++pl)
                aA[i][pl] = *(const short8*)&Al[pl][row][rpos];
        }
        #pragma unroll
        for (int j = 0; j < 2; ++j) {
            const int row = wvg * 32 + j * 16 + r16;
            #pragma unroll
            for (int pl = 0; pl < 2; ++pl)
                bB[j][pl] = *(const short8*)&Bl[pl][row][rpos];
            nb[j] = neg8(bB[j][1]);
        }
        // planes: 0=re 1=im.  re: Qr*Kr + Qi*(-Ki); im: Qr*Ki + Qi*Kr
        #pragma unroll
        for (int i = 0; i < 4; ++i)
            #pragma unroll
            for (int j = 0; j < 2; ++j) {
                accr[i][j] = MFMA16(aA[i][0], bB[j][0], accr[i][j]);
                accr[i][j] = MFMA16(aA[i][1], nb[j],    accr[i][j]);
                acci[i][j] = MFMA16(aA[i][0], bB[j][1], acci[i][j]);
                acci[i][j] = MFMA16(aA[i][1], bB[j][0], acci[i][j]);
            }
        __syncthreads();
    }

    const int rq = (lane >> 4) * 4;
    #pragma unroll
    for (int i = 0; i < 4; ++i)
        #pragma unroll
        for (int j = 0; j < 2; ++j)
            #pragma unroll
            for (int r = 0; r < 4; ++r) {
                const int f = f0 + wvf * 64 + i * 16 + rq + r;
                const int gg = g0 + wvg * 32 + j * 16 + r16;
                if (f < FF && gg < FF) {
                    const float ar = accr[i][j][r];
                    const float ai = acci[i][j][r];
                    att[((size_t)(b * FF + f)) * FF + gg] = ATT_SCALE * sqrtf(ar * ar + ai * ai);
                }
            }
}

// ---------------------------------------------------------------------------
// softmax over g per (b,f) row; fp32 in place + bf16 copy padded to GP.
// ---------------------------------------------------------------------------
__global__ __launch_bounds__(256) void softmax_rows(float* __restrict__ att,
                                                    bf16* __restrict__ att16)
{
    const int row = blockIdx.x;
    float* p = att + (size_t)row * FF;
    bf16* q = att16 + (size_t)row * GP;
    const int tid = threadIdx.x;
    const int lane = tid & 63, wid = tid >> 6;
    __shared__ float red[4];

    float m = -1e30f;
    for (int i = tid; i < FF; i += 256) m = fmaxf(m, p[i]);
    #pragma unroll
    for (int o = 32; o; o >>= 1) m = fmaxf(m, __shfl_down(m, o));
    if (lane == 0) red[wid] = m;
    __syncthreads();
    m = fmaxf(fmaxf(red[0], red[1]), fmaxf(red[2], red[3]));
    __syncthreads();

    float s = 0.f;
    for (int i = tid; i < FF; i += 256) { const float e = expf(p[i] - m); p[i] = e; s += e; }
    #pragma unroll
    for (int o = 32; o; o >>= 1) s += __shfl_down(s, o);
    if (lane == 0) red[wid] = s;
    __syncthreads();
    s = red[0] + red[1] + red[2] + red[3];
    const float inv = 1.f / s;
    for (int i = tid; i < GP; i += 256) {
        if (i < FF) {
            const float v = p[i] * inv;
            p[i] = v;
            q[i] = f2b(v);
        } else {
            q[i] = f2b(0.f);
        }
    }
}

// ---------------------------------------------------------------------------
// transpose V: Vf[b,g,d] float2 -> Vct[b,n,g] bf16 (n<512 re, else im).
// ---------------------------------------------------------------------------
__global__ __launch_bounds__(256) void transpose_v(const float2* __restrict__ Vf,
                                                   bf16* __restrict__ Vct)
{
    const int b = blockIdx.z;
    const int d0 = blockIdx.x * 32;
    const int g0 = blockIdx.y * 32;
    __shared__ float2 Tl[32][33];
    const int tid = threadIdx.x;

    for (int k = 0; k < 4; ++k) {
        const int idx = k * 256 + tid;
        const int lg = idx >> 5, ld = idx & 31;
        const int g = g0 + lg;
        Tl[lg][ld] = (g < FF) ? Vf[((size_t)(b * FF + g)) * 512 + d0 + ld]
                              : make_float2(0.f, 0.f);
    }
    __syncthreads();
    for (int k = 0; k < 4; ++k) {
        const int idx = k * 256 + tid;
        const int ld = idx >> 5, lg = idx & 31;
        const float2 v = Tl[lg][ld];
        Vct[((size_t)(b * 1024 + d0 + ld)) * GP + g0 + lg]       = f2b(v.x);
        Vct[((size_t)(b * 1024 + 512 + d0 + ld)) * GP + g0 + lg] = f2b(v.y);
    }
}

// ---------------------------------------------------------------------------
// ctx_mfma v3: 128f x 64n block, 4 waves (2f x 2n), wave 64f x 32n (4x2
// subtiles), XCD-swizzled flat grid. Cf[b,f,d] = sum_g attn * Vf.
// ---------------------------------------------------------------------------
__global__ __launch_bounds__(256, 2) void ctx_mfma(const bf16* __restrict__ att16,
                                                   const bf16* __restrict__ Vct,
                                                   float* __restrict__ Cf)
{
    const int flat = blockIdx.x;          // 1152 blocks
    const int b    = flat & 7;
    const int slot = flat >> 3;           // 0..143
    const int ft   = slot >> 4;           // 0..8
    const int nt   = slot & 15;           // 0..15
    const int f0 = ft * 128, n0 = nt * 64;

    const int tid = threadIdx.x;
    const int wv = tid >> 6, lane = tid & 63;
    const int wvf = wv >> 1, wvg = wv & 1;

    __shared__ __align__(16) bf16 Al[128][32];   // 8 KB
    __shared__ __align__(16) bf16 Bl[64][32];    // 4 KB

    f32x4 acc[4][2] = {};
    const int srow = tid >> 2, sq = tid & 3;
    const int r16 = lane & 15, cc = lane >> 4;
    const int rpos = (cc ^ ((r16 >> 1) & 3)) * 8;

    for (int kt = 0; kt < GP; kt += 32) {
        #pragma unroll
        for (int p = 0; p < 2; ++p) {
            const int row = p * 64 + srow;
            const int pos = (sq ^ ((row >> 1) & 3)) * 8;
            uint4 av = make_uint4(0, 0, 0, 0);
            if (f0 + row < FF)
                av = *(const uint4*)&att16[((size_t)(b * FF + f0 + row)) * GP + kt + sq * 8];
            *(uint4*)&Al[row][pos] = av;
        }
        {
            const int pos = (sq ^ ((srow >> 1) & 3)) * 8;
            *(uint4*)&Bl[srow][pos] =
                *(const uint4*)&Vct[((size_t)(b * 1024 + n0 + srow)) * GP + kt + sq * 8];
        }
        __syncthreads();

        short8 aA[4], bB[2];
        #pragma unroll
        for (int i = 0; i < 4; ++i)
            aA[i] = *(const short8*)&Al[wvf * 64 + i * 16 + r16][rpos];
        #pragma unroll
        for (int j = 0; j < 2; ++j)
            bB[j] = *(const short8*)&Bl[wvg * 32 + j * 16 + r16][rpos];
        #pragma unroll
        for (int i = 0; i < 4; ++i)
            #pragma unroll
            for (int j = 0; j < 2; ++j)
                acc[i][j] = MFMA16(aA[i], bB[j], acc[i][j]);
        __syncthreads();
    }

    const int rq = (lane >> 4) * 4;
    #pragma unroll
    for (int i = 0; i < 4; ++i)
        #pragma unroll
        for (int j = 0; j < 2; ++j)
            #pragma unroll
            for (int r = 0; r < 4; ++r) {
                const int f = f0 + wvf * 64 + i * 16 + rq + r;
                const int n = n0 + wvg * 32 + j * 16 + r16;
                if (f < FF) {
                    const int d = n & 511, im = n >> 9;
                    Cf[(((size_t)(b * FF + f)) * 512 + d) * 2 + im] = acc[i][j][r];
                }
            }
}

// ---------------------------------------------------------------------------
// launch — 4x33.65MB slots + 4MB weight region + bias + flag (~138.8 MB)
// ---------------------------------------------------------------------------
extern "C" void kernel_launch(void* const* d_in, const int* in_sizes, int n_in,
                              void* d_out, int out_size, void* d_ws, size_t ws_size,
                              hipStream_t stream)
{
    const void* x  = d_in[0];
    const void* Wq = d_in[1]; const void* bq = d_in[2];
    const void* Wk = d_in[3]; const void* bk = d_in[4];
    const void* Wv = d_in[5]; const void* bv = d_in[6];
    const void* Wo = d_in[7]; const void* bo = d_in[8];

    const size_t SLOT = 33652736;
    char* ws = (char*)d_ws;
    char* s0 = ws;               char* s1 = ws + SLOT;
    char* s2 = ws + 2 * SLOT;    char* s3 = ws + 3 * SLOT;
    char* wreg = ws + 4 * SLOT;
    bf16*  WT     = (bf16*)wreg;
    float* bias_f = (float*)(wreg + 4194304);
    int*   flag   = (int*)(wreg + 4194304 + 8192);

    bf16*   xh   = (bf16*)s3;
    bf16*   xl   = (bf16*)(s3 + 16777216);
    float*  Qt   = (float*)s0;  float* Kt = (float*)s1;  float* Vt = (float*)s2;
    float2* Qf   = (float2*)s3;
    bf16*   Asp  = (bf16*)s0;
    float2* Kf   = (float2*)s3;
    bf16*   Bsp  = (bf16*)s1;
    float2* Vf   = (float2*)s3;
    bf16*   Vct  = (bf16*)s2;
    float*  attn = (float*)s3;
    bf16*   att16= (bf16*)s0;
    float2* Cf   = (float2*)s1;
    bf16*   Ct16 = (bf16*)s2;

    const int SPLITQ_BLOCKS = (int)(((size_t)BB * FF * DD + 255) / 256);
    const int SPLITX_BLOCKS = (int)(((size_t)BB * LL * DD + 255) / 256);

    detect_dtype<<<1, 256, 0, stream>>>((const unsigned short*)x, flag);
    prep_bias<<<8, 256, 0, stream>>>(bq, bk, bv, bo, bias_f, flag);
    split_x<<<SPLITX_BLOCKS, 256, 0, stream>>>(x, xh, xl, flag);
    split_w_t<<<dim3(16, 16, 4), 256, 0, stream>>>(Wq, Wk, Wv, Wo, WT, flag);
    proj_mfma<<<dim3(128, 4, 3), 256, 0, stream>>>(xh, xl, WT, bias_f, Qt, Kt, Vt);
    rfft_cols<<<dim3(256, 8), 256, 0, stream>>>(Qt, Qf);
    conv_qk<<<SPLITQ_BLOCKS, 256, 0, stream>>>(Qf, Asp);
    rfft_cols<<<dim3(256, 8), 256, 0, stream>>>(Kt, Kf);
    conv_qk<<<SPLITQ_BLOCKS, 256, 0, stream>>>(Kf, Bsp);
    rfft_cols<<<dim3(256, 8), 256, 0, stream>>>(Vt, Vf);
    transpose_v<<<dim3(16, 33, 8), 256, 0, stream>>>(Vf, Vct);
    att_mfma<<<dim3(1224), 256, 0, stream>>>(Asp, Bsp, attn);
    softmax_rows<<<dim3(BB * FF), 256, 0, stream>>>(attn, att16);
    ctx_mfma<<<dim3(1152), 256, 0, stream>>>(att16, Vct, (float*)Cf);
    irfft_cols<<<dim3(256, 8), 256, 0, stream>>>(Cf, Ct16);
    out_mfma<<<dim3(128, 4), 256, 0, stream>>>(Ct16, WT + 3 * 524288, bias_f + 3 * 512,
                                               d_out, flag);
}